// Round 2
// baseline (490.928 us; speedup 1.0000x reference)
//
#include <hip/hip_runtime.h>

#define NWIDTH 299592
#define NOUT   51360

// ---------- Lyndon machinery (rebuilt every launch; deterministic) ----------

__device__ __forceinline__ bool is_lyndon(unsigned p, int n) {
  const unsigned nb = 3u * (unsigned)n;
  const unsigned mask = (1u << nb) - 1u;
  for (int k = 1; k < n; ++k) {
    unsigned rot = ((p << (3 * k)) & mask) | (p >> (nb - 3 * k));
    if (p >= rot) return false;   // strictly smaller than every proper rotation
  }
  return true;
}

__device__ __forceinline__ int lbound(const int* __restrict__ a, int lo, int hi, int v) {
  while (lo < hi) { int m = (lo + hi) >> 1; if (a[m] < v) lo = m + 1; else hi = m; }
  return lo;
}

// Levels 1..5 (8,64,512,4096,32768 positions): one block, shuffle-scan per level.
__global__ __launch_bounds__(1024) void lyndon_small(int* __restrict__ idx_table) {
  __shared__ int ws[16];
  const int tid = threadIdx.x, lane = tid & 63, wv = tid >> 6;
  const int sizes[5] = {8, 64, 512, 4096, 32768};
  const int offs[5]  = {0, 8, 72, 584, 4680};     // sig flat offsets
  const int bases[5] = {0, 8, 36, 204, 1212};     // out slot bases
  for (int li = 0; li < 5; ++li) {
    const int n = li + 1, sz = sizes[li];
    const int per = (sz + 1023) >> 10;
    const int start = tid * per;
    int c = 0;
    for (int j = 0; j < per; ++j) {
      int p = start + j;
      if (p < sz && is_lyndon((unsigned)p, n)) ++c;
    }
    int pref = c;                                  // wave inclusive scan
    for (int d = 1; d < 64; d <<= 1) { int t = __shfl_up(pref, d); if (lane >= d) pref += t; }
    if (lane == 63) ws[wv] = pref;
    __syncthreads();
    int wbase = 0;
    for (int i = 0; i < wv; ++i) wbase += ws[i];
    int excl = wbase + pref - c;
    int w = 0;
    for (int j = 0; j < per; ++j) {
      int p = start + j;
      if (p < sz && is_lyndon((unsigned)p, n)) {
        idx_table[bases[li] + excl + w] = offs[li] + p;
        ++w;
      }
    }
    __syncthreads();
  }
}

// Level 6: 262144 positions = 256 blocks x 1024 threads, two-pass scan.
__global__ __launch_bounds__(1024) void lyndon6_count(int* __restrict__ blkcnt) {
  const int tid = threadIdx.x;
  const unsigned p = blockIdx.x * 1024u + (unsigned)tid;
  bool f = is_lyndon(p, 6);
  unsigned long long m = __ballot(f);
  __shared__ int wsum[16];
  const int lane = tid & 63, wv = tid >> 6;
  if (lane == 0) wsum[wv] = __popcll(m);
  __syncthreads();
  if (tid == 0) {
    int s = 0;
    for (int i = 0; i < 16; ++i) s += wsum[i];
    blkcnt[blockIdx.x] = s;
  }
}

__global__ __launch_bounds__(256) void scan256(const int* __restrict__ blkcnt,
                                               int* __restrict__ blkoff) {
  __shared__ int t_[256];
  const int tid = threadIdx.x;
  int c = blkcnt[tid];
  t_[tid] = c;
  __syncthreads();
  for (int d = 1; d < 256; d <<= 1) {
    int t = (tid >= d) ? t_[tid - d] : 0;
    __syncthreads();
    t_[tid] += t;
    __syncthreads();
  }
  blkoff[tid] = t_[tid] - c;   // exclusive
}

__global__ __launch_bounds__(1024) void lyndon6_write(const int* __restrict__ blkoff,
                                                      int* __restrict__ idx_table) {
  const int tid = threadIdx.x;
  const unsigned p = blockIdx.x * 1024u + (unsigned)tid;
  bool f = is_lyndon(p, 6);
  unsigned long long m = __ballot(f);
  __shared__ int wsum[16];
  const int lane = tid & 63, wv = tid >> 6;
  if (lane == 0) wsum[wv] = __popcll(m);
  __syncthreads();
  if (tid == 0) {
    int s = 0;
    for (int i = 0; i < 16; ++i) { int t = wsum[i]; wsum[i] = s; s += t; }
  }
  __syncthreads();
  if (f) {
    int rank = blkoff[blockIdx.x] + wsum[wv] + __popcll(m & ((1ull << lane) - 1ull));
    idx_table[7764 + rank] = 37448 + (int)p;
  }
}

// ---------- main: per-(batch, first-letter) log-signature slice ----------
// sig level offsets: S1@0(8) S2@8(64) S3@72(512) S4@584(4096) S5@4680(32768) S6@37448(262144)
// LDS (32768 floats = 128 KiB), phase-overlapped:
//   iter phase : Plo[584] @0 (P2s@0,P3s@8,P4s@72) | s2c[64]@584 | s3c[528]@648 | s4c[4224]@1176
//   gather A   : L2@0(8) L3@8(64) L4@72(512) L5@584(4096)
//   gather B   : transposed L6: sm[(pl&31)*1024 + (pl>>5)]

__device__ __forceinline__ int pad32(int i) { return i + (i >> 5); }

__global__ __launch_bounds__(1024, 4) void logsig_main(const float* __restrict__ sig,
                                                       const int* __restrict__ idx_table,
                                                       float* __restrict__ out) {
  extern __shared__ float sm[];
  const int tid = threadIdx.x;
  const int bid = blockIdx.x;
  // XCD swizzle: all 8 j1-blocks of a batch land on one XCD (512 = 8 XCD x 64)
  const int xcd = bid & 7;
  const int g   = bid >> 3;
  const int b   = xcd * 8 + (g >> 3);
  const int j1  = g & 7;

  const float* __restrict__ S  = sig + (size_t)b * NWIDTH;
  const float* __restrict__ S2 = S + 8;
  const float* __restrict__ S3 = S + 72;
  const float* __restrict__ S4 = S + 584;
  const float* __restrict__ S5 = S + 4680;
  const float* __restrict__ S6 = S + 37448;

  float* Plo = sm;            // 584 floats
  float* s2c = sm + 584;      // 64
  float* s3c = sm + 648;      // 528 (padded 512)
  float* s4c = sm + 1176;     // 4224 (padded 4096)

  // ---- init (n = 1): P = S slices, L = S slices ----
  float s1v[8];
#pragma unroll
  for (int i = 0; i < 8; ++i) s1v[i] = S[i];
  float p1 = s1v[j1];
  const float s1j = p1;

  float l2 = 0.f, l3 = 0.f, l4 = 0.f;
  if (tid < 8)   { float v = S2[j1 * 8 + tid];   Plo[tid]      = v; l2 = v; }
  if (tid < 64)  { float v = S3[j1 * 64 + tid];  Plo[8 + tid]  = v; l3 = v; }
  if (tid < 512) { float v = S4[j1 * 512 + tid]; Plo[72 + tid] = v; l4 = v; }
  if (tid < 64)  s2c[tid] = S2[tid];
  if (tid < 512) s3c[pad32(tid)] = S3[tid];
  {
    float4 v = *(const float4*)(S4 + tid * 4);
    int i0 = tid * 4;
    s4c[pad32(i0)]     = v.x;
    s4c[pad32(i0 + 1)] = v.y;
    s4c[pad32(i0 + 2)] = v.z;
    s4c[pad32(i0 + 3)] = v.w;
  }
  float p5[4], l5[4];
  {
    float4 v = *(const float4*)(S5 + j1 * 4096 + tid * 4);
    p5[0] = v.x; p5[1] = v.y; p5[2] = v.z; p5[3] = v.w;
    l5[0] = v.x; l5[1] = v.y; l5[2] = v.z; l5[3] = v.w;
  }
  float l6[32];
  {
    const float4* s6v = (const float4*)(S6 + (size_t)j1 * 32768 + tid * 32);
#pragma unroll
    for (int v = 0; v < 8; ++v) {
      float4 x = s6v[v];
      l6[4 * v] = x.x; l6[4 * v + 1] = x.y; l6[4 * v + 2] = x.z; l6[4 * v + 3] = x.w;
    }
  }
  // hoisted n=2, i=1 term for level 6 (feeds only L6, never P): -1/2 * p1 * S5[r]
  {
    const float c2p1 = -0.5f * p1;
    const float4* s5v = (const float4*)(S5 + (size_t)tid * 32);
#pragma unroll
    for (int v = 0; v < 8; ++v) {
      float4 x = s5v[v];
      l6[4 * v]     += c2p1 * x.x;
      l6[4 * v + 1] += c2p1 * x.y;
      l6[4 * v + 2] += c2p1 * x.z;
      l6[4 * v + 3] += c2p1 * x.w;
    }
  }
  __syncthreads();

  // ---- Horner iterations: P <- P (x) S, L += coef_n * P ----
  const float coefs[7] = {0.f, 0.f, -0.5f, 1.f / 3.f, -0.25f, 0.2f, -1.f / 6.f};
#pragma unroll
  for (int n = 2; n <= 6; ++n) {
    const float coef = coefs[n];
    // level 6: accumulate into l6 IMMEDIATELY (no a6 array across barrier)
#pragma unroll
    for (int e = 0; e < 32; ++e) {
      const int r = (tid << 5) + e;
      float acc = p5[e >> 3] * s1v[e & 7];                        // i=5, always
      if (n <= 5) acc += Plo[72 + (r >> 6)] * s2c[r & 63];        // i=4
      if (n <= 4) acc += Plo[8 + (r >> 9)] * s3c[pad32(r & 511)]; // i=3
      if (n <= 3) acc += Plo[(r >> 12)] * s4c[pad32(r & 4095)];   // i=2
      l6[e] += coef * acc;
    }
    // level 5: only np5[4] survives the barrier
    float np5[4];
#pragma unroll
    for (int e = 0; e < 4; ++e) {
      const int q = (tid << 2) + e;
      float acc = 0.f;
      if (n <= 5) acc += Plo[72 + (q >> 3)] * s1v[q & 7];         // i=4
      if (n <= 4) acc += Plo[8 + (q >> 6)] * s2c[q & 63];         // i=3
      if (n <= 3) acc += Plo[(q >> 9)] * s3c[pad32(q & 511)];     // i=2
      if (n == 2) acc += p1 * s4c[pad32(q)];                      // i=1
      np5[e] = acc;
      l5[e] += coef * acc;
    }
    // levels 4,3,2 (LDS slices, owner threads)
    float t4 = 0.f, t3 = 0.f, t2 = 0.f;
    if (tid < 512) {
      if (n <= 4) t4 += Plo[8 + (tid >> 3)] * s1v[tid & 7];       // i=3
      if (n <= 3) t4 += Plo[(tid >> 6)] * s2c[tid & 63];          // i=2
      if (n == 2) t4 += p1 * s3c[pad32(tid)];                     // i=1
    }
    if (tid < 64) {
      if (n <= 3) t3 += Plo[(tid >> 3)] * s1v[tid & 7];           // i=2
      if (n == 2) t3 += p1 * s2c[tid];                            // i=1
    }
    if (tid < 8) {
      if (n == 2) t2 = p1 * s1v[tid];                             // i=1
    }
    __syncthreads();  // all reads of P_old (Plo) complete
    if (tid < 512) Plo[72 + tid] = t4;
    if (tid < 64)  Plo[8 + tid]  = t3;
    if (tid < 8)   Plo[tid]      = t2;
#pragma unroll
    for (int e = 0; e < 4; ++e) p5[e] = np5[e];
    l4 += coef * t4; l3 += coef * t3; l2 += coef * t2;
    __syncthreads();  // P_new visible before next iteration
  }

  // ---- gather phase ----
  float* outb = out + (size_t)b * NOUT;
  // dump L2..L5 (overwrites dead iteration state; loop-end barrier ordered the reads)
  if (tid < 8)   sm[tid]      = l2;
  if (tid < 64)  sm[8 + tid]  = l3;
  if (tid < 512) sm[72 + tid] = l4;
  {
    int q4 = tid * 4;
    sm[584 + q4] = l5[0]; sm[584 + q4 + 1] = l5[1];
    sm[584 + q4 + 2] = l5[2]; sm[584 + q4 + 3] = l5[3];
  }
  if (tid == 0) outb[j1] = s1j;   // level-1 Lyndon word j1
  __syncthreads();

  const int goff[7]   = {0, 0, 8, 72, 584, 4680, 37448};
  const int gbase[7]  = {0, 0, 8, 36, 204, 1212, 7764};
  const int gcnt[7]   = {0, 8, 28, 168, 1008, 6552, 43596};
  const int gsub[7]   = {0, 1, 8, 64, 512, 4096, 32768};
  const int ldsoff[6] = {0, 0, 0, 8, 72, 584};
#pragma unroll
  for (int k = 2; k <= 5; ++k) {
    const int lo = gbase[k], hi = gbase[k] + gcnt[k];
    const int v0 = goff[k] + j1 * gsub[k];
    const int v1 = v0 + gsub[k];
    const int a0 = lbound(idx_table, lo, hi, v0);
    const int a1 = lbound(idx_table, lo, hi, v1);
    for (int o = a0 + tid; o < a1; o += 1024) {
      int pl = idx_table[o] - v0;
      outb[o] = sm[ldsoff[k] + pl];
    }
  }
  __syncthreads();
  // dump L6 transposed (conflict-free writes), then gather level 6
#pragma unroll
  for (int e = 0; e < 32; ++e) sm[e * 1024 + tid] = l6[e];
  __syncthreads();
  {
    const int lo = gbase[6], hi = gbase[6] + gcnt[6];
    const int v0 = goff[6] + j1 * gsub[6];
    const int v1 = v0 + gsub[6];
    const int a0 = lbound(idx_table, lo, hi, v0);
    const int a1 = lbound(idx_table, lo, hi, v1);
    for (int o = a0 + tid; o < a1; o += 1024) {
      int pl = idx_table[o] - v0;
      outb[o] = sm[(pl & 31) * 1024 + (pl >> 5)];
    }
  }
}

// ---------- launch ----------

extern "C" void kernel_launch(void* const* d_in, const int* in_sizes, int n_in,
                              void* d_out, int out_size, void* d_ws, size_t ws_size,
                              hipStream_t stream) {
  const float* sig = (const float*)d_in[0];
  float* out = (float*)d_out;
  int* idx_table = (int*)d_ws;           // 51360 ints
  int* blkcnt = idx_table + NOUT;        // 256
  int* blkoff = blkcnt + 256;            // 256

  (void)hipFuncSetAttribute((const void*)logsig_main,
                            hipFuncAttributeMaxDynamicSharedMemorySize, 131072);

  lyndon_small<<<1, 1024, 0, stream>>>(idx_table);
  lyndon6_count<<<256, 1024, 0, stream>>>(blkcnt);
  scan256<<<1, 256, 0, stream>>>(blkcnt, blkoff);
  lyndon6_write<<<256, 1024, 0, stream>>>(blkoff, idx_table);
  logsig_main<<<512, 1024, 131072, stream>>>(sig, idx_table, out);
}

// Round 3
// 490.596 us; speedup vs baseline: 1.0007x; 1.0007x over previous
//
#include <hip/hip_runtime.h>

#define NWIDTH 299592
#define NOUT   51360

// ---------- Lyndon machinery (rebuilt every launch; deterministic) ----------

__device__ __forceinline__ bool is_lyndon(unsigned p, int n) {
  const unsigned nb = 3u * (unsigned)n;
  const unsigned mask = (1u << nb) - 1u;
  for (int k = 1; k < n; ++k) {
    unsigned rot = ((p << (3 * k)) & mask) | (p >> (nb - 3 * k));
    if (p >= rot) return false;   // strictly smaller than every proper rotation
  }
  return true;
}

__device__ __forceinline__ int lbound(const int* __restrict__ a, int lo, int hi, int v) {
  while (lo < hi) { int m = (lo + hi) >> 1; if (a[m] < v) lo = m + 1; else hi = m; }
  return lo;
}

// blocks 0..255: level-6 count (262144 positions). block 256: levels 1..5 direct.
__global__ __launch_bounds__(1024) void lyndon_stage1(int* __restrict__ idx_table,
                                                      int* __restrict__ blkcnt) {
  const int tid = threadIdx.x, lane = tid & 63, wv = tid >> 6;
  if (blockIdx.x < 256) {
    const unsigned p = blockIdx.x * 1024u + (unsigned)tid;
    bool f = is_lyndon(p, 6);
    unsigned long long m = __ballot(f);
    __shared__ int wsum[16];
    if (lane == 0) wsum[wv] = __popcll(m);
    __syncthreads();
    if (tid == 0) {
      int s = 0;
      for (int i = 0; i < 16; ++i) s += wsum[i];
      blkcnt[blockIdx.x] = s;
    }
    return;
  }
  // levels 1..5: shuffle-scan per level
  __shared__ int ws[16];
  const int sizes[5] = {8, 64, 512, 4096, 32768};
  const int offs[5]  = {0, 8, 72, 584, 4680};     // sig flat offsets
  const int bases[5] = {0, 8, 36, 204, 1212};     // out slot bases
  for (int li = 0; li < 5; ++li) {
    const int n = li + 1, sz = sizes[li];
    const int per = (sz + 1023) >> 10;
    const int start = tid * per;
    int c = 0;
    for (int j = 0; j < per; ++j) {
      int p = start + j;
      if (p < sz && is_lyndon((unsigned)p, n)) ++c;
    }
    int pref = c;                                  // wave inclusive scan
    for (int d = 1; d < 64; d <<= 1) { int t = __shfl_up(pref, d); if (lane >= d) pref += t; }
    if (lane == 63) ws[wv] = pref;
    __syncthreads();
    int wbase = 0;
    for (int i = 0; i < wv; ++i) wbase += ws[i];
    int excl = wbase + pref - c;
    int w = 0;
    for (int j = 0; j < per; ++j) {
      int p = start + j;
      if (p < sz && is_lyndon((unsigned)p, n)) {
        idx_table[bases[li] + excl + w] = offs[li] + p;
        ++w;
      }
    }
    __syncthreads();
  }
}

__global__ __launch_bounds__(256) void scan256(const int* __restrict__ blkcnt,
                                               int* __restrict__ blkoff) {
  __shared__ int t_[256];
  const int tid = threadIdx.x;
  int c = blkcnt[tid];
  t_[tid] = c;
  __syncthreads();
  for (int d = 1; d < 256; d <<= 1) {
    int t = (tid >= d) ? t_[tid - d] : 0;
    __syncthreads();
    t_[tid] += t;
    __syncthreads();
  }
  blkoff[tid] = t_[tid] - c;   // exclusive
}

__global__ __launch_bounds__(1024) void lyndon6_write(const int* __restrict__ blkoff,
                                                      int* __restrict__ idx_table) {
  const int tid = threadIdx.x;
  const unsigned p = blockIdx.x * 1024u + (unsigned)tid;
  bool f = is_lyndon(p, 6);
  unsigned long long m = __ballot(f);
  __shared__ int wsum[16];
  const int lane = tid & 63, wv = tid >> 6;
  if (lane == 0) wsum[wv] = __popcll(m);
  __syncthreads();
  if (tid == 0) {
    int s = 0;
    for (int i = 0; i < 16; ++i) { int t = wsum[i]; wsum[i] = s; s += t; }
  }
  __syncthreads();
  if (f) {
    int rank = blkoff[blockIdx.x] + wsum[wv] + __popcll(m & ((1ull << lane) - 1ull));
    idx_table[7764 + rank] = 37448 + (int)p;
  }
}

// ---------- main: per-(batch, first-letter) log-signature slice ----------
// sig level offsets: S1@0(8) S2@8(64) S3@72(512) S4@584(4096) S5@4680(32768) S6@37448(262144)
// LDS (32768 floats = 128 KiB), phase-overlapped:
//   iter phase : Plo[584] @0 (P2s@0,P3s@8,P4s@72) | s2c[64]@584 | s3c[528]@648 | s4c[4224]@1176
//   gather A   : L2@0(8) L3@8(64) L4@72(512) L5@584(4096)
//   gather B   : transposed L6: sm[(pl&31)*1024 + (pl>>5)]

__device__ __forceinline__ int pad32(int i) { return i + (i >> 5); }

__global__ __launch_bounds__(1024)
__attribute__((amdgpu_waves_per_eu(4, 4)))   // pin 4 waves/EU -> 128-VGPR budget, kill spills
void logsig_main(const float* __restrict__ sig,
                 const int* __restrict__ idx_table,
                 float* __restrict__ out) {
  extern __shared__ float sm[];
  const int tid = threadIdx.x;
  const int bid = blockIdx.x;
  // XCD swizzle: all 8 j1-blocks of a batch land on one XCD (512 = 8 XCD x 64)
  const int xcd = bid & 7;
  const int g   = bid >> 3;
  const int b   = xcd * 8 + (g >> 3);
  const int j1  = g & 7;

  const float* __restrict__ S  = sig + (size_t)b * NWIDTH;
  const float* __restrict__ S2 = S + 8;
  const float* __restrict__ S3 = S + 72;
  const float* __restrict__ S4 = S + 584;
  const float* __restrict__ S5 = S + 4680;
  const float* __restrict__ S6 = S + 37448;

  float* Plo = sm;            // 584 floats
  float* s2c = sm + 584;      // 64
  float* s3c = sm + 648;      // 528 (padded 512)
  float* s4c = sm + 1176;     // 4224 (padded 4096)

  // ---- init (n = 1): P = S slices, L = S slices ----
  float s1v[8];
#pragma unroll
  for (int i = 0; i < 8; ++i) s1v[i] = S[i];
  float p1 = s1v[j1];
  const float s1j = p1;

  float l2 = 0.f, l3 = 0.f, l4 = 0.f;
  if (tid < 8)   { float v = S2[j1 * 8 + tid];   Plo[tid]      = v; l2 = v; }
  if (tid < 64)  { float v = S3[j1 * 64 + tid];  Plo[8 + tid]  = v; l3 = v; }
  if (tid < 512) { float v = S4[j1 * 512 + tid]; Plo[72 + tid] = v; l4 = v; }
  if (tid < 64)  s2c[tid] = S2[tid];
  if (tid < 512) s3c[pad32(tid)] = S3[tid];
  {
    float4 v = *(const float4*)(S4 + tid * 4);
    int i0 = tid * 4;
    s4c[pad32(i0)]     = v.x;
    s4c[pad32(i0 + 1)] = v.y;
    s4c[pad32(i0 + 2)] = v.z;
    s4c[pad32(i0 + 3)] = v.w;
  }
  float p5[4], l5[4];
  {
    float4 v = *(const float4*)(S5 + j1 * 4096 + tid * 4);
    p5[0] = v.x; p5[1] = v.y; p5[2] = v.z; p5[3] = v.w;
    l5[0] = v.x; l5[1] = v.y; l5[2] = v.z; l5[3] = v.w;
  }
  float l6[32];
  {
    const float4* s6v = (const float4*)(S6 + (size_t)j1 * 32768 + tid * 32);
#pragma unroll
    for (int v = 0; v < 8; ++v) {
      float4 x = s6v[v];
      l6[4 * v] = x.x; l6[4 * v + 1] = x.y; l6[4 * v + 2] = x.z; l6[4 * v + 3] = x.w;
    }
  }
  // hoisted n=2, i=1 term for level 6 (feeds only L6, never P): -1/2 * p1 * S5[r]
  {
    const float c2p1 = -0.5f * p1;
    const float4* s5v = (const float4*)(S5 + (size_t)tid * 32);
#pragma unroll
    for (int v = 0; v < 8; ++v) {
      float4 x = s5v[v];
      l6[4 * v]     += c2p1 * x.x;
      l6[4 * v + 1] += c2p1 * x.y;
      l6[4 * v + 2] += c2p1 * x.z;
      l6[4 * v + 3] += c2p1 * x.w;
    }
  }
  __syncthreads();

  // ---- Horner iterations: P <- P (x) S, L += coef_n * P ----
  const float coefs[7] = {0.f, 0.f, -0.5f, 1.f / 3.f, -0.25f, 0.2f, -1.f / 6.f};
#pragma unroll
  for (int n = 2; n <= 6; ++n) {
    const float coef = coefs[n];
    // e-invariant P_old prefix values (shared by the L6 and L5 loops):
    //   r=(tid<<5)+e: r>>6 = tid>>1, r>>9 = tid>>4, r>>12 = tid>>7
    //   q=(tid<<2)+e: q>>3 = tid>>1, q>>6 = tid>>4, q>>9  = tid>>7
    const float ph4 = (n <= 5) ? Plo[72 + (tid >> 1)] : 0.f;  // P4[j2j3j4]
    const float ph3 = (n <= 4) ? Plo[8 + (tid >> 4)]  : 0.f;  // P3[j2j3]
    const float ph2 = (n <= 3) ? Plo[tid >> 7]        : 0.f;  // P2[j2]
    // level 6: accumulate into l6 IMMEDIATELY (no a6 array across barrier)
#pragma unroll
    for (int e = 0; e < 32; ++e) {
      const int r = (tid << 5) + e;
      float acc = p5[e >> 3] * s1v[e & 7];                     // i=5, always
      if (n <= 5) acc += ph4 * s2c[r & 63];                    // i=4
      if (n <= 4) acc += ph3 * s3c[pad32(r & 511)];            // i=3
      if (n <= 3) acc += ph2 * s4c[pad32(r & 4095)];           // i=2
      l6[e] += coef * acc;
    }
    // level 5: only np5[4] survives the barrier
    float np5[4];
#pragma unroll
    for (int e = 0; e < 4; ++e) {
      const int q = (tid << 2) + e;
      float acc = 0.f;
      if (n <= 5) acc += ph4 * s1v[q & 7];                     // i=4
      if (n <= 4) acc += ph3 * s2c[q & 63];                    // i=3
      if (n <= 3) acc += ph2 * s3c[pad32(q & 511)];            // i=2
      if (n == 2) acc += p1 * s4c[pad32(q)];                   // i=1
      np5[e] = acc;
      l5[e] += coef * acc;
    }
    // levels 4,3,2 (LDS slices, owner threads)
    float t4 = 0.f, t3 = 0.f, t2 = 0.f;
    if (tid < 512) {
      if (n <= 4) t4 += Plo[8 + (tid >> 3)] * s1v[tid & 7];    // i=3
      if (n <= 3) t4 += Plo[(tid >> 6)] * s2c[tid & 63];       // i=2
      if (n == 2) t4 += p1 * s3c[pad32(tid)];                  // i=1
    }
    if (tid < 64) {
      if (n <= 3) t3 += Plo[(tid >> 3)] * s1v[tid & 7];        // i=2
      if (n == 2) t3 += p1 * s2c[tid];                         // i=1
    }
    if (tid < 8) {
      if (n == 2) t2 = p1 * s1v[tid];                          // i=1
    }
    __syncthreads();  // all reads of P_old (Plo) complete
    if (tid < 512) Plo[72 + tid] = t4;
    if (tid < 64)  Plo[8 + tid]  = t3;
    if (tid < 8)   Plo[tid]      = t2;
#pragma unroll
    for (int e = 0; e < 4; ++e) p5[e] = np5[e];
    l4 += coef * t4; l3 += coef * t3; l2 += coef * t2;
    __syncthreads();  // P_new visible before next iteration
  }

  // ---- gather phase ----
  float* outb = out + (size_t)b * NOUT;
  // dump L2..L5 (overwrites dead iteration state; loop-end barrier ordered the reads)
  if (tid < 8)   sm[tid]      = l2;
  if (tid < 64)  sm[8 + tid]  = l3;
  if (tid < 512) sm[72 + tid] = l4;
  {
    int q4 = tid * 4;
    sm[584 + q4] = l5[0]; sm[584 + q4 + 1] = l5[1];
    sm[584 + q4 + 2] = l5[2]; sm[584 + q4 + 3] = l5[3];
  }
  if (tid == 0) outb[j1] = s1j;   // level-1 Lyndon word j1
  __syncthreads();

  const int goff[7]   = {0, 0, 8, 72, 584, 4680, 37448};
  const int gbase[7]  = {0, 0, 8, 36, 204, 1212, 7764};
  const int gcnt[7]   = {0, 8, 28, 168, 1008, 6552, 43596};
  const int gsub[7]   = {0, 1, 8, 64, 512, 4096, 32768};
  const int ldsoff[6] = {0, 0, 0, 8, 72, 584};
#pragma unroll
  for (int k = 2; k <= 5; ++k) {
    const int lo = gbase[k], hi = gbase[k] + gcnt[k];
    const int v0 = goff[k] + j1 * gsub[k];
    const int v1 = v0 + gsub[k];
    const int a0 = lbound(idx_table, lo, hi, v0);
    const int a1 = lbound(idx_table, lo, hi, v1);
    for (int o = a0 + tid; o < a1; o += 1024) {
      int pl = idx_table[o] - v0;
      outb[o] = sm[ldsoff[k] + pl];
    }
  }
  __syncthreads();
  // dump L6 transposed (conflict-free writes), then gather level 6
#pragma unroll
  for (int e = 0; e < 32; ++e) sm[e * 1024 + tid] = l6[e];
  __syncthreads();
  {
    const int lo = gbase[6], hi = gbase[6] + gcnt[6];
    const int v0 = goff[6] + j1 * gsub[6];
    const int v1 = v0 + gsub[6];
    const int a0 = lbound(idx_table, lo, hi, v0);
    const int a1 = lbound(idx_table, lo, hi, v1);
    for (int o = a0 + tid; o < a1; o += 1024) {
      int pl = idx_table[o] - v0;
      outb[o] = sm[(pl & 31) * 1024 + (pl >> 5)];
    }
  }
}

// ---------- launch ----------

extern "C" void kernel_launch(void* const* d_in, const int* in_sizes, int n_in,
                              void* d_out, int out_size, void* d_ws, size_t ws_size,
                              hipStream_t stream) {
  const float* sig = (const float*)d_in[0];
  float* out = (float*)d_out;
  int* idx_table = (int*)d_ws;           // 51360 ints
  int* blkcnt = idx_table + NOUT;        // 256
  int* blkoff = blkcnt + 256;            // 256

  (void)hipFuncSetAttribute((const void*)logsig_main,
                            hipFuncAttributeMaxDynamicSharedMemorySize, 131072);

  lyndon_stage1<<<257, 1024, 0, stream>>>(idx_table, blkcnt);
  scan256<<<1, 256, 0, stream>>>(blkcnt, blkoff);
  lyndon6_write<<<256, 1024, 0, stream>>>(blkoff, idx_table);
  logsig_main<<<512, 1024, 131072, stream>>>(sig, idx_table, out);
}

// Round 4
// 110.086 us; speedup vs baseline: 4.4595x; 4.4565x over previous
//
#include <hip/hip_runtime.h>

#define NWIDTH 299592
#define NOUT   51360

// ---------- Lyndon machinery (rebuilt every launch; deterministic) ----------

__device__ __forceinline__ bool is_lyndon(unsigned p, int n) {
  const unsigned nb = 3u * (unsigned)n;
  const unsigned mask = (1u << nb) - 1u;
  for (int k = 1; k < n; ++k) {
    unsigned rot = ((p << (3 * k)) & mask) | (p >> (nb - 3 * k));
    if (p >= rot) return false;   // strictly smaller than every proper rotation
  }
  return true;
}

__device__ __forceinline__ int lbound(const int* __restrict__ a, int lo, int hi, int v) {
  while (lo < hi) { int m = (lo + hi) >> 1; if (a[m] < v) lo = m + 1; else hi = m; }
  return lo;
}

// blocks 0..255: level-6 count (262144 positions). block 256: levels 1..5 direct.
__global__ __launch_bounds__(1024) void lyndon_stage1(int* __restrict__ idx_table,
                                                      int* __restrict__ blkcnt) {
  const int tid = threadIdx.x, lane = tid & 63, wv = tid >> 6;
  if (blockIdx.x < 256) {
    const unsigned p = blockIdx.x * 1024u + (unsigned)tid;
    bool f = is_lyndon(p, 6);
    unsigned long long m = __ballot(f);
    __shared__ int wsum[16];
    if (lane == 0) wsum[wv] = __popcll(m);
    __syncthreads();
    if (tid == 0) {
      int s = 0;
      for (int i = 0; i < 16; ++i) s += wsum[i];
      blkcnt[blockIdx.x] = s;
    }
    return;
  }
  // levels 1..5: shuffle-scan per level
  __shared__ int ws[16];
  const int sizes[5] = {8, 64, 512, 4096, 32768};
  const int offs[5]  = {0, 8, 72, 584, 4680};     // sig flat offsets
  const int bases[5] = {0, 8, 36, 204, 1212};     // out slot bases
  for (int li = 0; li < 5; ++li) {
    const int n = li + 1, sz = sizes[li];
    const int per = (sz + 1023) >> 10;
    const int start = tid * per;
    int c = 0;
    for (int j = 0; j < per; ++j) {
      int p = start + j;
      if (p < sz && is_lyndon((unsigned)p, n)) ++c;
    }
    int pref = c;                                  // wave inclusive scan
    for (int d = 1; d < 64; d <<= 1) { int t = __shfl_up(pref, d); if (lane >= d) pref += t; }
    if (lane == 63) ws[wv] = pref;
    __syncthreads();
    int wbase = 0;
    for (int i = 0; i < wv; ++i) wbase += ws[i];
    int excl = wbase + pref - c;
    int w = 0;
    for (int j = 0; j < per; ++j) {
      int p = start + j;
      if (p < sz && is_lyndon((unsigned)p, n)) {
        idx_table[bases[li] + excl + w] = offs[li] + p;
        ++w;
      }
    }
    __syncthreads();
  }
}

__global__ __launch_bounds__(256) void scan256(const int* __restrict__ blkcnt,
                                               int* __restrict__ blkoff) {
  __shared__ int t_[256];
  const int tid = threadIdx.x;
  int c = blkcnt[tid];
  t_[tid] = c;
  __syncthreads();
  for (int d = 1; d < 256; d <<= 1) {
    int t = (tid >= d) ? t_[tid - d] : 0;
    __syncthreads();
    t_[tid] += t;
    __syncthreads();
  }
  blkoff[tid] = t_[tid] - c;   // exclusive
}

__global__ __launch_bounds__(1024) void lyndon6_write(const int* __restrict__ blkoff,
                                                      int* __restrict__ idx_table) {
  const int tid = threadIdx.x;
  const unsigned p = blockIdx.x * 1024u + (unsigned)tid;
  bool f = is_lyndon(p, 6);
  unsigned long long m = __ballot(f);
  __shared__ int wsum[16];
  const int lane = tid & 63, wv = tid >> 6;
  if (lane == 0) wsum[wv] = __popcll(m);
  __syncthreads();
  if (tid == 0) {
    int s = 0;
    for (int i = 0; i < 16; ++i) { int t = wsum[i]; wsum[i] = s; s += t; }
  }
  __syncthreads();
  if (f) {
    int rank = blkoff[blockIdx.x] + wsum[wv] + __popcll(m & ((1ull << lane) - 1ull));
    idx_table[7764 + rank] = 37448 + (int)p;
  }
}

// ---------- main: per-(batch, first-letter) log-signature slice ----------
//
// Key identity: L = S + sum_n coef_n P^{(n)}, P^{(n)} = S^{(x)n}. Distribute the
// n-sum through the graded product:
//   L6 = S6 + A5(x)S1 + A4(x)S2 + A3(x)S3 + A2(x)S4 + coef2*p1*S5
// where A_i = sum_m coef_{m+1} P_i^{(m)} (levels 1..5 only; A1 = coef2*S1).
// Same A-arrays give L5..L2 in closed form. So the Horner loop iterates only
// P2..P5 (LDS + 4 regs/thread) and accumulates A2..A5; L6 is evaluated
// on-the-fly at the Lyndon gather points. No 32-float register slices -> no
// scratch spill at the default 64-VGPR budget.
//
// sig level offsets: S1@0(8) S2@8(64) S3@72(512) S4@584(4096) S5@4680(32768) S6@37448(262144)
// LDS layout (14176 floats = 56.7 KiB static; 2 blocks/CU):
//   PLO@0[584]: P2@0 P3@8 P4@72 during Horner; L2/L3/L4 after.
//   L5@584[4096] | A2@4680[8] A3@4688[64] A4@4752[512] A5@5264[4096]
//   S2C@9360[64] | S3C@9424[528 pad] | S4C@9952[4224 pad]

#define SM_PLO 0
#define SM_L5  584
#define SM_A2  4680
#define SM_A3  4688
#define SM_A4  4752
#define SM_A5  5264
#define SM_S2  9360
#define SM_S3  9424
#define SM_S4  9952
#define SM_TOT 14176

__device__ __forceinline__ int pad32(int i) { return i + (i >> 5); }

__global__ __launch_bounds__(1024)
void logsig_main(const float* __restrict__ sig,
                 const int* __restrict__ idx_table,
                 float* __restrict__ out) {
  __shared__ float sm[SM_TOT];
  const int tid = threadIdx.x;
  const int bid = blockIdx.x;
  // XCD swizzle: all 8 j1-blocks of a batch land on one XCD (512 = 8 XCD x 64)
  const int xcd = bid & 7;
  const int g   = bid >> 3;
  const int b   = xcd * 8 + (g >> 3);
  const int j1  = g & 7;

  const float* __restrict__ S  = sig + (size_t)b * NWIDTH;
  const float* __restrict__ S2 = S + 8;
  const float* __restrict__ S3 = S + 72;
  const float* __restrict__ S4 = S + 584;
  const float* __restrict__ S5 = S + 4680;
  const float* __restrict__ S6 = S + 37448;

  // ---- init ----
  float s1v[8];
#pragma unroll
  for (int i = 0; i < 8; ++i) s1v[i] = S[i];
  const float p1 = s1v[j1];

  if (tid < 8)   sm[SM_PLO + tid]      = S2[j1 * 8 + tid];
  if (tid < 64)  sm[SM_PLO + 8 + tid]  = S3[j1 * 64 + tid];
  if (tid < 512) sm[SM_PLO + 72 + tid] = S4[j1 * 512 + tid];
  if (tid < 64)  sm[SM_S2 + tid] = S2[tid];
  if (tid < 512) sm[SM_S3 + pad32(tid)] = S3[tid];
  {
    float4 v = *(const float4*)(S4 + tid * 4);
    int i0 = tid * 4;
    sm[SM_S4 + pad32(i0)]     = v.x;
    sm[SM_S4 + pad32(i0 + 1)] = v.y;
    sm[SM_S4 + pad32(i0 + 2)] = v.z;
    sm[SM_S4 + pad32(i0 + 3)] = v.w;
  }
  float p5[4], l5i[4];
  {
    float4 v = *(const float4*)(S5 + j1 * 4096 + tid * 4);
    p5[0] = v.x; p5[1] = v.y; p5[2] = v.z; p5[3] = v.w;
    l5i[0] = v.x; l5i[1] = v.y; l5i[2] = v.z; l5i[3] = v.w;
  }
  float a5[4] = {0.f, 0.f, 0.f, 0.f};
  float a4 = 0.f, a3 = 0.f, a2 = 0.f;
  __syncthreads();

  // ---- Horner on levels 2..5 only, accumulating A = sum coef_n P^{(n-1)} ----
  const float coefs[7] = {0.f, 0.f, -0.5f, 1.f / 3.f, -0.25f, 0.2f, -1.f / 6.f};
#pragma unroll
  for (int n = 2; n <= 5; ++n) {
    const float coef = coefs[n];
    // A-accumulate from P^{(n-1)} (current P)
#pragma unroll
    for (int e = 0; e < 4; ++e) a5[e] += coef * p5[e];
    if (tid < 512) a4 += coef * sm[SM_PLO + 72 + tid];
    if (tid < 64)  a3 += coef * sm[SM_PLO + 8 + tid];
    if (tid < 8)   a2 += coef * sm[SM_PLO + tid];
    // P-update: P^{(n)} = (P^{(n-1)} (x) S), levels 2..5
    //   q=(tid<<2)+e: q>>3 = tid>>1, q>>6 = tid>>4, q>>9 = tid>>7 (e-invariant)
    const float ph4 = sm[SM_PLO + 72 + (tid >> 1)];
    const float ph3 = sm[SM_PLO + 8 + (tid >> 4)];
    const float ph2 = sm[SM_PLO + (tid >> 7)];
    float np5[4];
#pragma unroll
    for (int e = 0; e < 4; ++e) {
      const int q = (tid << 2) + e;
      float acc = ph4 * s1v[q & 7] + ph3 * sm[SM_S2 + (q & 63)]
                + ph2 * sm[SM_S3 + pad32(q & 511)];
      if (n == 2) acc += p1 * sm[SM_S4 + pad32(q)];
      np5[e] = acc;
    }
    float t4 = 0.f, t3 = 0.f, t2 = 0.f;
    if (tid < 512) {
      t4 = sm[SM_PLO + 8 + (tid >> 3)] * s1v[tid & 7]
         + sm[SM_PLO + (tid >> 6)] * sm[SM_S2 + (tid & 63)];
      if (n == 2) t4 += p1 * sm[SM_S3 + pad32(tid)];
    }
    if (tid < 64) {
      t3 = sm[SM_PLO + (tid >> 3)] * s1v[tid & 7];
      if (n == 2) t3 += p1 * sm[SM_S2 + tid];
    }
    if (tid < 8) {
      if (n == 2) t2 = p1 * s1v[tid];
    }
    __syncthreads();  // all reads of P_old complete
    if (tid < 512) sm[SM_PLO + 72 + tid] = t4;
    if (tid < 64)  sm[SM_PLO + 8 + tid]  = t3;
    if (tid < 8)   sm[SM_PLO + tid]      = t2;
#pragma unroll
    for (int e = 0; e < 4; ++e) p5[e] = np5[e];
    __syncthreads();  // P_new visible
  }
  // n = 6 contributes only via level-5 history (P4^{(5)}=P3^{(5)}=P2^{(5)}=0)
#pragma unroll
  for (int e = 0; e < 4; ++e) a5[e] += coefs[6] * p5[e];

  // ---- dump A arrays ----
  if (tid < 8)   sm[SM_A2 + tid] = a2;
  if (tid < 64)  sm[SM_A3 + tid] = a3;
  if (tid < 512) sm[SM_A4 + tid] = a4;
  *(float4*)(sm + SM_A5 + tid * 4) = make_float4(a5[0], a5[1], a5[2], a5[3]);
  __syncthreads();

  // ---- closed-form L2..L5 into LDS ----
  const float c2p1 = -0.5f * p1;
  if (tid < 8)
    sm[SM_PLO + tid] = sm[SM_S2 + j1 * 8 + tid] + c2p1 * s1v[tid];
  if (tid < 64)
    sm[SM_PLO + 8 + tid] = sm[SM_S3 + pad32(j1 * 64 + tid)]
                         + sm[SM_A2 + (tid >> 3)] * s1v[tid & 7]
                         + c2p1 * sm[SM_S2 + tid];
  if (tid < 512)
    sm[SM_PLO + 72 + tid] = sm[SM_S4 + pad32(j1 * 512 + tid)]
                          + sm[SM_A3 + (tid >> 3)] * s1v[tid & 7]
                          + sm[SM_A2 + (tid >> 6)] * sm[SM_S2 + (tid & 63)]
                          + c2p1 * sm[SM_S3 + pad32(tid)];
  {
    float l5v[4];
#pragma unroll
    for (int e = 0; e < 4; ++e) {
      const int q = (tid << 2) + e;
      l5v[e] = l5i[e]
             + sm[SM_A4 + (tid >> 1)] * s1v[q & 7]
             + sm[SM_A3 + (tid >> 4)] * sm[SM_S2 + (q & 63)]
             + sm[SM_A2 + (tid >> 7)] * sm[SM_S3 + pad32(q & 511)]
             + c2p1 * sm[SM_S4 + pad32(q)];
    }
    *(float4*)(sm + SM_L5 + tid * 4) = make_float4(l5v[0], l5v[1], l5v[2], l5v[3]);
  }
  float* outb = out + (size_t)b * NOUT;
  if (tid == 0) outb[j1] = p1;   // level-1 Lyndon word j1
  __syncthreads();

  // ---- gather ----
  const int goff[7]   = {0, 0, 8, 72, 584, 4680, 37448};
  const int gbase[7]  = {0, 0, 8, 36, 204, 1212, 7764};
  const int gcnt[7]   = {0, 8, 28, 168, 1008, 6552, 43596};
  const int gsub[7]   = {0, 1, 8, 64, 512, 4096, 32768};
  const int ldsoff[6] = {0, 0, 0, 8, 72, 584};
#pragma unroll
  for (int k = 2; k <= 5; ++k) {
    const int lo = gbase[k], hi = gbase[k] + gcnt[k];
    const int v0 = goff[k] + j1 * gsub[k];
    const int v1 = v0 + gsub[k];
    const int a0 = lbound(idx_table, lo, hi, v0);
    const int a1 = lbound(idx_table, lo, hi, v1);
    for (int o = a0 + tid; o < a1; o += 1024) {
      int pl = idx_table[o] - v0;
      outb[o] = sm[ldsoff[k] + pl];
    }
  }
  // level 6: evaluate on the fly at each Lyndon point
  {
    const int lo = gbase[6], hi = gbase[6] + gcnt[6];
    const int v0 = goff[6] + j1 * gsub[6];
    const int v1 = v0 + gsub[6];
    const int a0 = lbound(idx_table, lo, hi, v0);
    const int a1 = lbound(idx_table, lo, hi, v1);
    const float* __restrict__ S6j = S6 + (size_t)j1 * 32768;
    for (int o = a0 + tid; o < a1; o += 1024) {
      int pl = idx_table[o] - v0;
      float v = S6j[pl]
              + sm[SM_A5 + (pl >> 3)] * s1v[pl & 7]
              + sm[SM_A4 + (pl >> 6)] * sm[SM_S2 + (pl & 63)]
              + sm[SM_A3 + (pl >> 9)] * sm[SM_S3 + pad32(pl & 511)]
              + sm[SM_A2 + (pl >> 12)] * sm[SM_S4 + pad32(pl & 4095)]
              + c2p1 * S5[pl];
      outb[o] = v;
    }
  }
}

// ---------- launch ----------

extern "C" void kernel_launch(void* const* d_in, const int* in_sizes, int n_in,
                              void* d_out, int out_size, void* d_ws, size_t ws_size,
                              hipStream_t stream) {
  const float* sig = (const float*)d_in[0];
  float* out = (float*)d_out;
  int* idx_table = (int*)d_ws;           // 51360 ints
  int* blkcnt = idx_table + NOUT;        // 256
  int* blkoff = blkcnt + 256;            // 256

  lyndon_stage1<<<257, 1024, 0, stream>>>(idx_table, blkcnt);
  scan256<<<1, 256, 0, stream>>>(blkcnt, blkoff);
  lyndon6_write<<<256, 1024, 0, stream>>>(blkoff, idx_table);
  logsig_main<<<512, 1024, 0, stream>>>(sig, idx_table, out);
}

// Round 5
// 97.719 us; speedup vs baseline: 5.0239x; 1.1266x over previous
//
#include <hip/hip_runtime.h>

#define NWIDTH 299592
#define NOUT   51360

typedef unsigned long long ull;

// ---------- Lyndon machinery (rebuilt every launch; deterministic) ----------

__device__ __forceinline__ bool is_lyndon(unsigned p, int n) {
  const unsigned nb = 3u * (unsigned)n;
  const unsigned mask = (1u << nb) - 1u;
  for (int k = 1; k < n; ++k) {
    unsigned rot = ((p << (3 * k)) & mask) | (p >> (nb - 3 * k));
    if (p >= rot) return false;   // strictly smaller than every proper rotation
  }
  return true;
}

__device__ __forceinline__ int lbound(const int* __restrict__ a, int lo, int hi, int v) {
  while (lo < hi) { int m = (lo + hi) >> 1; if (a[m] < v) lo = m + 1; else hi = m; }
  return lo;
}

// blocks 0..255: level-6 count (262144 positions). block 256: levels 1..5 direct.
__global__ __launch_bounds__(1024) void lyndon_stage1(int* __restrict__ idx_table,
                                                      int* __restrict__ blkcnt) {
  const int tid = threadIdx.x, lane = tid & 63, wv = tid >> 6;
  if (blockIdx.x < 256) {
    const unsigned p = blockIdx.x * 1024u + (unsigned)tid;
    bool f = is_lyndon(p, 6);
    unsigned long long m = __ballot(f);
    __shared__ int wsum[16];
    if (lane == 0) wsum[wv] = __popcll(m);
    __syncthreads();
    if (tid == 0) {
      int s = 0;
      for (int i = 0; i < 16; ++i) s += wsum[i];
      blkcnt[blockIdx.x] = s;
    }
    return;
  }
  // levels 1..5: shuffle-scan per level (only levels 2..5 are consumed via idx_table)
  __shared__ int ws[16];
  const int sizes[5] = {8, 64, 512, 4096, 32768};
  const int offs[5]  = {0, 8, 72, 584, 4680};     // sig flat offsets
  const int bases[5] = {0, 8, 36, 204, 1212};     // out slot bases
  for (int li = 0; li < 5; ++li) {
    const int n = li + 1, sz = sizes[li];
    const int per = (sz + 1023) >> 10;
    const int start = tid * per;
    int c = 0;
    for (int j = 0; j < per; ++j) {
      int p = start + j;
      if (p < sz && is_lyndon((unsigned)p, n)) ++c;
    }
    int pref = c;                                  // wave inclusive scan
    for (int d = 1; d < 64; d <<= 1) { int t = __shfl_up(pref, d); if (lane >= d) pref += t; }
    if (lane == 63) ws[wv] = pref;
    __syncthreads();
    int wbase = 0;
    for (int i = 0; i < wv; ++i) wbase += ws[i];
    int excl = wbase + pref - c;
    int w = 0;
    for (int j = 0; j < per; ++j) {
      int p = start + j;
      if (p < sz && is_lyndon((unsigned)p, n)) {
        idx_table[bases[li] + excl + w] = offs[li] + p;
        ++w;
      }
    }
    __syncthreads();
  }
}

// Per-64-group Lyndon mask + exclusive global rank offset; block prefix by inline
// reduction over blkcnt; block 0 also fills the level-2..5 gather range table.
__global__ __launch_bounds__(1024) void lyndon6_finish(const int* __restrict__ blkcnt,
                                                       const int* __restrict__ idx_table,
                                                       ull* __restrict__ mask64,
                                                       int* __restrict__ grp_off,
                                                       int* __restrict__ range_tab) {
  const int tid = threadIdx.x, lane = tid & 63, wv = tid >> 6;
  __shared__ int wred[16];
  __shared__ int wsum[16];
  __shared__ int s_blockoff;
  // block offset = sum blkcnt[0..bid)  (bid <= 255 < 1024)
  int partial = (tid < (int)blockIdx.x) ? blkcnt[tid] : 0;
  for (int d = 32; d; d >>= 1) partial += __shfl_down(partial, d);
  if (lane == 0) wred[wv] = partial;
  __syncthreads();
  if (tid == 0) {
    int s = 0;
    for (int i = 0; i < 16; ++i) s += wred[i];
    s_blockoff = s;
  }
  const unsigned p = blockIdx.x * 1024u + (unsigned)tid;
  bool f = is_lyndon(p, 6);
  unsigned long long m = __ballot(f);
  if (lane == 0) wsum[wv] = __popcll(m);
  __syncthreads();
  if (tid == 0) {
    int s = 0;
    for (int i = 0; i < 16; ++i) { int t = wsum[i]; wsum[i] = s; s += t; }
  }
  __syncthreads();
  if (lane == 0) {
    mask64[blockIdx.x * 16 + wv]  = m;
    grp_off[blockIdx.x * 16 + wv] = s_blockoff + wsum[wv];
  }
  // range table: levels 2..5, per j1, [a0,a1) in idx_table slot space
  if (blockIdx.x == 0 && tid < 64) {
    const int goff[4]  = {8, 72, 584, 4680};
    const int gbase[4] = {8, 36, 204, 1212};
    const int gcnt[4]  = {28, 168, 1008, 6552};
    const int gsub[4]  = {8, 64, 512, 4096};
    const int ki = tid >> 4, j = (tid >> 1) & 7, which = tid & 1;
    const int v = goff[ki] + (j + which) * gsub[ki];
    range_tab[tid] = lbound(idx_table, gbase[ki], gbase[ki] + gcnt[ki], v);
  }
}

// ---------- main: per-(batch, first-letter) log-signature slice ----------
//
// L = S + sum_n coef_n S^{(x)n}. With A_i = sum_m coef_{m+1} P_i^{(m)} (levels
// 1..5 only), L6 = S6 + A5(x)S1 + A4(x)S2 + A3(x)S3 + A2(x)S4 + coef2*p1*S5 is
// evaluated by STREAMING the j1-slice coalesced; Lyndon selection + output slot
// come from the ballot-rank tables (wave-uniform mask64/grp_off loads).
//
// sig level offsets: S1@0(8) S2@8(64) S3@72(512) S4@584(4096) S5@4680(32768) S6@37448(262144)
// LDS layout (14176 floats = 56.7 KiB; 2 blocks/CU):
//   PLO@0[584]: P2@0 P3@8 P4@72 during Horner; L2/L3/L4 after.
//   L5@584[4096] | A2@4680[8] A3@4688[64] A4@4752[512] A5@5264[4096]
//   S2C@9360[64] | S3C@9424[528 pad] | S4C@9952[4224 pad]

#define SM_PLO 0
#define SM_L5  584
#define SM_A2  4680
#define SM_A3  4688
#define SM_A4  4752
#define SM_A5  5264
#define SM_S2  9360
#define SM_S3  9424
#define SM_S4  9952
#define SM_TOT 14176

__device__ __forceinline__ int pad32(int i) { return i + (i >> 5); }

__global__ __launch_bounds__(1024)
void logsig_main(const float* __restrict__ sig,
                 const int* __restrict__ idx_table,
                 const ull* __restrict__ mask64,
                 const int* __restrict__ grp_off,
                 const int* __restrict__ range_tab,
                 float* __restrict__ out) {
  __shared__ float sm[SM_TOT];
  const int tid = threadIdx.x;
  const int lane = tid & 63, wv = tid >> 6;
  const int bid = blockIdx.x;
  // XCD swizzle: all 8 j1-blocks of a batch land on one XCD (512 = 8 XCD x 64)
  const int xcd = bid & 7;
  const int g   = bid >> 3;
  const int b   = xcd * 8 + (g >> 3);
  const int j1  = g & 7;

  const float* __restrict__ S  = sig + (size_t)b * NWIDTH;
  const float* __restrict__ S2 = S + 8;
  const float* __restrict__ S3 = S + 72;
  const float* __restrict__ S4 = S + 584;
  const float* __restrict__ S5 = S + 4680;
  const float* __restrict__ S6 = S + 37448;

  // ---- init ----
  float s1v[8];
#pragma unroll
  for (int i = 0; i < 8; ++i) s1v[i] = S[i];
  const float p1 = s1v[j1];

  if (tid < 8)   sm[SM_PLO + tid]      = S2[j1 * 8 + tid];
  if (tid < 64)  sm[SM_PLO + 8 + tid]  = S3[j1 * 64 + tid];
  if (tid < 512) sm[SM_PLO + 72 + tid] = S4[j1 * 512 + tid];
  if (tid < 64)  sm[SM_S2 + tid] = S2[tid];
  if (tid < 512) sm[SM_S3 + pad32(tid)] = S3[tid];
  {
    float4 v = *(const float4*)(S4 + tid * 4);
    int i0 = tid * 4;
    sm[SM_S4 + pad32(i0)]     = v.x;
    sm[SM_S4 + pad32(i0 + 1)] = v.y;
    sm[SM_S4 + pad32(i0 + 2)] = v.z;
    sm[SM_S4 + pad32(i0 + 3)] = v.w;
  }
  float p5[4], l5i[4];
  {
    float4 v = *(const float4*)(S5 + j1 * 4096 + tid * 4);
    p5[0] = v.x; p5[1] = v.y; p5[2] = v.z; p5[3] = v.w;
    l5i[0] = v.x; l5i[1] = v.y; l5i[2] = v.z; l5i[3] = v.w;
  }
  float a5[4] = {0.f, 0.f, 0.f, 0.f};
  float a4 = 0.f, a3 = 0.f, a2 = 0.f;
  __syncthreads();

  // ---- Horner on levels 2..5 only, accumulating A = sum coef_n P^{(n-1)} ----
  const float coefs[7] = {0.f, 0.f, -0.5f, 1.f / 3.f, -0.25f, 0.2f, -1.f / 6.f};
#pragma unroll
  for (int n = 2; n <= 5; ++n) {
    const float coef = coefs[n];
#pragma unroll
    for (int e = 0; e < 4; ++e) a5[e] += coef * p5[e];
    if (tid < 512) a4 += coef * sm[SM_PLO + 72 + tid];
    if (tid < 64)  a3 += coef * sm[SM_PLO + 8 + tid];
    if (tid < 8)   a2 += coef * sm[SM_PLO + tid];
    //   q=(tid<<2)+e: q>>3 = tid>>1, q>>6 = tid>>4, q>>9 = tid>>7 (e-invariant)
    const float ph4 = sm[SM_PLO + 72 + (tid >> 1)];
    const float ph3 = sm[SM_PLO + 8 + (tid >> 4)];
    const float ph2 = sm[SM_PLO + (tid >> 7)];
    float np5[4];
#pragma unroll
    for (int e = 0; e < 4; ++e) {
      const int q = (tid << 2) + e;
      float acc = ph4 * s1v[q & 7] + ph3 * sm[SM_S2 + (q & 63)]
                + ph2 * sm[SM_S3 + pad32(q & 511)];
      if (n == 2) acc += p1 * sm[SM_S4 + pad32(q)];
      np5[e] = acc;
    }
    float t4 = 0.f, t3 = 0.f, t2 = 0.f;
    if (tid < 512) {
      t4 = sm[SM_PLO + 8 + (tid >> 3)] * s1v[tid & 7]
         + sm[SM_PLO + (tid >> 6)] * sm[SM_S2 + (tid & 63)];
      if (n == 2) t4 += p1 * sm[SM_S3 + pad32(tid)];
    }
    if (tid < 64) {
      t3 = sm[SM_PLO + (tid >> 3)] * s1v[tid & 7];
      if (n == 2) t3 += p1 * sm[SM_S2 + tid];
    }
    if (tid < 8) {
      if (n == 2) t2 = p1 * s1v[tid];
    }
    __syncthreads();  // all reads of P_old complete
    if (tid < 512) sm[SM_PLO + 72 + tid] = t4;
    if (tid < 64)  sm[SM_PLO + 8 + tid]  = t3;
    if (tid < 8)   sm[SM_PLO + tid]      = t2;
#pragma unroll
    for (int e = 0; e < 4; ++e) p5[e] = np5[e];
    __syncthreads();  // P_new visible
  }
  // n = 6 contributes only via level-5 history
#pragma unroll
  for (int e = 0; e < 4; ++e) a5[e] += coefs[6] * p5[e];

  // ---- dump A arrays ----
  if (tid < 8)   sm[SM_A2 + tid] = a2;
  if (tid < 64)  sm[SM_A3 + tid] = a3;
  if (tid < 512) sm[SM_A4 + tid] = a4;
  *(float4*)(sm + SM_A5 + tid * 4) = make_float4(a5[0], a5[1], a5[2], a5[3]);
  __syncthreads();

  // ---- closed-form L2..L5 into LDS ----
  const float c2p1 = -0.5f * p1;
  if (tid < 8)
    sm[SM_PLO + tid] = sm[SM_S2 + j1 * 8 + tid] + c2p1 * s1v[tid];
  if (tid < 64)
    sm[SM_PLO + 8 + tid] = sm[SM_S3 + pad32(j1 * 64 + tid)]
                         + sm[SM_A2 + (tid >> 3)] * s1v[tid & 7]
                         + c2p1 * sm[SM_S2 + tid];
  if (tid < 512)
    sm[SM_PLO + 72 + tid] = sm[SM_S4 + pad32(j1 * 512 + tid)]
                          + sm[SM_A3 + (tid >> 3)] * s1v[tid & 7]
                          + sm[SM_A2 + (tid >> 6)] * sm[SM_S2 + (tid & 63)]
                          + c2p1 * sm[SM_S3 + pad32(tid)];
  {
    float l5v[4];
#pragma unroll
    for (int e = 0; e < 4; ++e) {
      const int q = (tid << 2) + e;
      l5v[e] = l5i[e]
             + sm[SM_A4 + (tid >> 1)] * s1v[q & 7]
             + sm[SM_A3 + (tid >> 4)] * sm[SM_S2 + (q & 63)]
             + sm[SM_A2 + (tid >> 7)] * sm[SM_S3 + pad32(q & 511)]
             + c2p1 * sm[SM_S4 + pad32(q)];
    }
    *(float4*)(sm + SM_L5 + tid * 4) = make_float4(l5v[0], l5v[1], l5v[2], l5v[3]);
  }
  float* outb = out + (size_t)b * NOUT;
  if (tid == 0) outb[j1] = p1;   // level-1 Lyndon word j1
  __syncthreads();

  // ---- gather levels 2..5 via precomputed ranges (no binary search) ----
  const int goff[6]   = {0, 0, 8, 72, 584, 4680};
  const int gsub[6]   = {0, 1, 8, 64, 512, 4096};
  const int ldsoff[6] = {0, 0, 0, 8, 72, 584};
#pragma unroll
  for (int k = 2; k <= 5; ++k) {
    const int rb = (k - 2) * 16 + j1 * 2;
    const int a0 = range_tab[rb];
    const int a1 = range_tab[rb + 1];
    const int v0 = goff[k] + j1 * gsub[k];
    for (int o = a0 + tid; o < a1; o += 1024) {
      int pl = idx_table[o] - v0;
      outb[o] = sm[ldsoff[k] + pl];
    }
  }
  // ---- level 6: coalesced stream + ballot-rank scatter ----
  {
    const float* __restrict__ S6j = S6 + (size_t)j1 * 32768;
    const ull* __restrict__ mk = mask64 + j1 * 512;
    const int* __restrict__ go = grp_off + j1 * 512;
    const ull lmask = (1ull << lane) - 1ull;
#pragma unroll 4
    for (int it = 0; it < 32; ++it) {
      const int pl = it * 1024 + tid;
      const int gg = it * 16 + wv;          // wave-uniform group
      const ull m  = mk[gg];
      const int gofs = go[gg];
      float v = S6j[pl]
              + sm[SM_A5 + (pl >> 3)] * s1v[pl & 7]
              + sm[SM_A4 + (pl >> 6)] * sm[SM_S2 + (pl & 63)]
              + sm[SM_A3 + (pl >> 9)] * sm[SM_S3 + pad32(pl & 511)]
              + sm[SM_A2 + (pl >> 12)] * sm[SM_S4 + pad32(pl & 4095)]
              + c2p1 * S5[pl];
      if ((m >> lane) & 1ull)
        outb[7764 + gofs + __popcll(m & lmask)] = v;
    }
  }
}

// ---------- launch ----------
// d_ws layout (16B-aligned head): mask64[4096] ull | idx_table[51360] int |
// blkcnt[256] int | grp_off[4096] int | range_tab[64] int  (~256 KB total)

extern "C" void kernel_launch(void* const* d_in, const int* in_sizes, int n_in,
                              void* d_out, int out_size, void* d_ws, size_t ws_size,
                              hipStream_t stream) {
  const float* sig = (const float*)d_in[0];
  float* out = (float*)d_out;
  ull* mask64    = (ull*)d_ws;                       // 4096 ull
  int* idx_table = (int*)(mask64 + 4096);            // 51360 int
  int* blkcnt    = idx_table + NOUT;                 // 256
  int* grp_off   = blkcnt + 256;                     // 4096
  int* range_tab = grp_off + 4096;                   // 64

  lyndon_stage1<<<257, 1024, 0, stream>>>(idx_table, blkcnt);
  lyndon6_finish<<<256, 1024, 0, stream>>>(blkcnt, idx_table, mask64, grp_off, range_tab);
  logsig_main<<<512, 1024, 0, stream>>>(sig, idx_table, mask64, grp_off, range_tab, out);
}

// Round 6
// 79.428 us; speedup vs baseline: 6.1808x; 1.2303x over previous
//
#include <hip/hip_runtime.h>

#define NWIDTH 299592
#define NOUT   51360

typedef unsigned long long ull;

// ---------- Lyndon machinery (rebuilt every launch; deterministic) ----------

__device__ __forceinline__ bool is_lyndon(unsigned p, int n) {
  const unsigned nb = 3u * (unsigned)n;
  const unsigned mask = (1u << nb) - 1u;
  for (int k = 1; k < n; ++k) {
    unsigned rot = ((p << (3 * k)) & mask) | (p >> (nb - 3 * k));
    if (p >= rot) return false;   // strictly smaller than every proper rotation
  }
  return true;
}

__device__ __forceinline__ int lbound(const int* __restrict__ a, int lo, int hi, int v) {
  while (lo < hi) { int m = (lo + hi) >> 1; if (a[m] < v) lo = m + 1; else hi = m; }
  return lo;
}

// blocks 0..255: level-6 count (262144 positions). block 256: levels 1..5 direct.
__global__ __launch_bounds__(1024) void lyndon_stage1(int* __restrict__ idx_table,
                                                      int* __restrict__ blkcnt) {
  const int tid = threadIdx.x, lane = tid & 63, wv = tid >> 6;
  if (blockIdx.x < 256) {
    const unsigned p = blockIdx.x * 1024u + (unsigned)tid;
    bool f = is_lyndon(p, 6);
    unsigned long long m = __ballot(f);
    __shared__ int wsum[16];
    if (lane == 0) wsum[wv] = __popcll(m);
    __syncthreads();
    if (tid == 0) {
      int s = 0;
      for (int i = 0; i < 16; ++i) s += wsum[i];
      blkcnt[blockIdx.x] = s;
    }
    return;
  }
  // levels 1..5: shuffle-scan per level (unrolled so const arrays stay static)
  __shared__ int ws[16];
  const int sizes[5] = {8, 64, 512, 4096, 32768};
  const int offs[5]  = {0, 8, 72, 584, 4680};     // sig flat offsets
  const int bases[5] = {0, 8, 36, 204, 1212};     // out slot bases
#pragma unroll
  for (int li = 0; li < 5; ++li) {
    const int n = li + 1, sz = sizes[li];
    const int per = (sz + 1023) >> 10;
    const int start = tid * per;
    int c = 0;
    for (int j = 0; j < per; ++j) {
      int p = start + j;
      if (p < sz && is_lyndon((unsigned)p, n)) ++c;
    }
    int pref = c;                                  // wave inclusive scan
    for (int d = 1; d < 64; d <<= 1) { int t = __shfl_up(pref, d); if (lane >= d) pref += t; }
    if (lane == 63) ws[wv] = pref;
    __syncthreads();
    int wbase = 0;
    for (int i = 0; i < wv; ++i) wbase += ws[i];
    int excl = wbase + pref - c;
    int w = 0;
    for (int j = 0; j < per; ++j) {
      int p = start + j;
      if (p < sz && is_lyndon((unsigned)p, n)) {
        idx_table[bases[li] + excl + w] = offs[li] + p;
        ++w;
      }
    }
    __syncthreads();
  }
}

// Per-64-group Lyndon mask + exclusive global rank offset; block prefix by inline
// reduction over blkcnt; block 0 also fills the level-2..5 gather range table.
__global__ __launch_bounds__(1024) void lyndon6_finish(const int* __restrict__ blkcnt,
                                                       const int* __restrict__ idx_table,
                                                       ull* __restrict__ mask64,
                                                       int* __restrict__ grp_off,
                                                       int* __restrict__ range_tab) {
  const int tid = threadIdx.x, lane = tid & 63, wv = tid >> 6;
  __shared__ int wred[16];
  __shared__ int wsum[16];
  __shared__ int s_blockoff;
  int partial = (tid < (int)blockIdx.x) ? blkcnt[tid] : 0;
  for (int d = 32; d; d >>= 1) partial += __shfl_down(partial, d);
  if (lane == 0) wred[wv] = partial;
  __syncthreads();
  if (tid == 0) {
    int s = 0;
    for (int i = 0; i < 16; ++i) s += wred[i];
    s_blockoff = s;
  }
  const unsigned p = blockIdx.x * 1024u + (unsigned)tid;
  bool f = is_lyndon(p, 6);
  unsigned long long m = __ballot(f);
  if (lane == 0) wsum[wv] = __popcll(m);
  __syncthreads();
  if (tid == 0) {
    int s = 0;
    for (int i = 0; i < 16; ++i) { int t = wsum[i]; wsum[i] = s; s += t; }
  }
  __syncthreads();
  if (lane == 0) {
    mask64[blockIdx.x * 16 + wv]  = m;
    grp_off[blockIdx.x * 16 + wv] = s_blockoff + wsum[wv];
  }
  // range table: levels 2..5, per j1, [a0,a1) in idx_table slot space
  if (blockIdx.x == 0 && tid < 64) {
    const int goff[4]  = {8, 72, 584, 4680};
    const int gbase[4] = {8, 36, 204, 1212};
    const int gcnt[4]  = {28, 168, 1008, 6552};
    const int gsub[4]  = {8, 64, 512, 4096};
    const int ki = tid >> 4, j = (tid >> 1) & 7, which = tid & 1;
    const int v = goff[ki] + (j + which) * gsub[ki];
    range_tab[tid] = lbound(idx_table, gbase[ki], gbase[ki] + gcnt[ki], v);
  }
}

// ---------- main: per-(batch, first-letter) log-signature slice ----------
//
// L = S + sum_n coef_n S^{(x)n}. With A_i = sum_m coef_{m+1} P_i^{(m)} (levels
// 1..5 only), L6 = S6 + A5(x)S1 + A4(x)S2 + A3(x)S3 + A2(x)S4 + coef2*p1*S5 is
// evaluated by STREAMING the j1-slice coalesced (float4); Lyndon selection +
// output slot come from ballot-rank tables. S1 lives in LDS (NO runtime-indexed
// register arrays anywhere -> no scratch).
//
// sig level offsets: S1@0(8) S2@8(64) S3@72(512) S4@584(4096) S5@4680(32768) S6@37448(262144)
// LDS layout (14184 floats = 56.7 KiB; 2 blocks/CU):
//   PLO@0[584]: P2@0 P3@8 P4@72 during Horner; L2/L3/L4 after.
//   L5@584[4096] | A2@4680[8] A3@4688[64] A4@4752[512] A5@5264[4096]
//   S2C@9360[64] | S3C@9424[528 pad] | S4C@9952[4224 pad] | S1C@14176[8]

#define SM_PLO 0
#define SM_L5  584
#define SM_A2  4680
#define SM_A3  4688
#define SM_A4  4752
#define SM_A5  5264
#define SM_S2  9360
#define SM_S3  9424
#define SM_S4  9952
#define SM_S1  14176
#define SM_TOT 14184

__device__ __forceinline__ int pad32(int i) { return i + (i >> 5); }

__global__ __launch_bounds__(1024)
void logsig_main(const float* __restrict__ sig,
                 const int* __restrict__ idx_table,
                 const ull* __restrict__ mask64,
                 const int* __restrict__ grp_off,
                 const int* __restrict__ range_tab,
                 float* __restrict__ out) {
  __shared__ float sm[SM_TOT];
  const int tid = threadIdx.x;
  const int bid = blockIdx.x;
  // XCD swizzle: all 8 j1-blocks of a batch land on one XCD (512 = 8 XCD x 64)
  const int xcd = bid & 7;
  const int g   = bid >> 3;
  const int b   = xcd * 8 + (g >> 3);
  const int j1  = g & 7;

  const float* __restrict__ S  = sig + (size_t)b * NWIDTH;
  const float* __restrict__ S2 = S + 8;
  const float* __restrict__ S3 = S + 72;
  const float* __restrict__ S4 = S + 584;
  const float* __restrict__ S5 = S + 4680;
  const float* __restrict__ S6 = S + 37448;

  const float p1 = S[j1];

  // ---- init ----
  if (tid < 8)   sm[SM_S1 + tid] = S[tid];
  if (tid < 8)   sm[SM_PLO + tid]      = S2[j1 * 8 + tid];
  if (tid < 64)  sm[SM_PLO + 8 + tid]  = S3[j1 * 64 + tid];
  if (tid < 512) sm[SM_PLO + 72 + tid] = S4[j1 * 512 + tid];
  if (tid < 64)  sm[SM_S2 + tid] = S2[tid];
  if (tid < 512) sm[SM_S3 + pad32(tid)] = S3[tid];
  {
    float4 v = *(const float4*)(S4 + tid * 4);
    int i0 = tid * 4;
    sm[SM_S4 + pad32(i0)]     = v.x;
    sm[SM_S4 + pad32(i0 + 1)] = v.y;
    sm[SM_S4 + pad32(i0 + 2)] = v.z;
    sm[SM_S4 + pad32(i0 + 3)] = v.w;
  }
  float p5[4], l5i[4];
  {
    float4 v = *(const float4*)(S5 + j1 * 4096 + tid * 4);
    p5[0] = v.x; p5[1] = v.y; p5[2] = v.z; p5[3] = v.w;
    l5i[0] = v.x; l5i[1] = v.y; l5i[2] = v.z; l5i[3] = v.w;
  }
  float a5[4] = {0.f, 0.f, 0.f, 0.f};
  float a4 = 0.f, a3 = 0.f, a2 = 0.f;
  __syncthreads();

  // loop-invariant S1 values, statically indexed from here on:
  //   q=(tid<<2)+e: q&7 = ((tid&1)<<2)+e ; tid&7 for owner-thread paths
  float s1q[4];
#pragma unroll
  for (int e = 0; e < 4; ++e) s1q[e] = sm[SM_S1 + ((tid & 1) << 2) + e];
  const float s1t = sm[SM_S1 + (tid & 7)];

  // ---- Horner on levels 2..5 only, accumulating A = sum coef_n P^{(n-1)} ----
  const float coefs[7] = {0.f, 0.f, -0.5f, 1.f / 3.f, -0.25f, 0.2f, -1.f / 6.f};
#pragma unroll
  for (int n = 2; n <= 5; ++n) {
    const float coef = coefs[n];
#pragma unroll
    for (int e = 0; e < 4; ++e) a5[e] += coef * p5[e];
    if (tid < 512) a4 += coef * sm[SM_PLO + 72 + tid];
    if (tid < 64)  a3 += coef * sm[SM_PLO + 8 + tid];
    if (tid < 8)   a2 += coef * sm[SM_PLO + tid];
    //   q=(tid<<2)+e: q>>3 = tid>>1, q>>6 = tid>>4, q>>9 = tid>>7 (e-invariant)
    const float ph4 = sm[SM_PLO + 72 + (tid >> 1)];
    const float ph3 = sm[SM_PLO + 8 + (tid >> 4)];
    const float ph2 = sm[SM_PLO + (tid >> 7)];
    float np5[4];
#pragma unroll
    for (int e = 0; e < 4; ++e) {
      const int q = (tid << 2) + e;
      float acc = ph4 * s1q[e] + ph3 * sm[SM_S2 + (q & 63)]
                + ph2 * sm[SM_S3 + pad32(q & 511)];
      if (n == 2) acc += p1 * sm[SM_S4 + pad32(q)];
      np5[e] = acc;
    }
    float t4 = 0.f, t3 = 0.f, t2 = 0.f;
    if (tid < 512) {
      t4 = sm[SM_PLO + 8 + (tid >> 3)] * s1t
         + sm[SM_PLO + (tid >> 6)] * sm[SM_S2 + (tid & 63)];
      if (n == 2) t4 += p1 * sm[SM_S3 + pad32(tid)];
    }
    if (tid < 64) {
      t3 = sm[SM_PLO + (tid >> 3)] * s1t;
      if (n == 2) t3 += p1 * sm[SM_S2 + tid];
    }
    if (tid < 8) {
      if (n == 2) t2 = p1 * s1t;   // s1t = S1[tid] for tid<8
    }
    __syncthreads();  // all reads of P_old complete
    if (tid < 512) sm[SM_PLO + 72 + tid] = t4;
    if (tid < 64)  sm[SM_PLO + 8 + tid]  = t3;
    if (tid < 8)   sm[SM_PLO + tid]      = t2;
#pragma unroll
    for (int e = 0; e < 4; ++e) p5[e] = np5[e];
    __syncthreads();  // P_new visible
  }
  // n = 6 contributes only via level-5 history
#pragma unroll
  for (int e = 0; e < 4; ++e) a5[e] += coefs[6] * p5[e];

  // ---- dump A arrays ----
  if (tid < 8)   sm[SM_A2 + tid] = a2;
  if (tid < 64)  sm[SM_A3 + tid] = a3;
  if (tid < 512) sm[SM_A4 + tid] = a4;
  *(float4*)(sm + SM_A5 + tid * 4) = make_float4(a5[0], a5[1], a5[2], a5[3]);
  __syncthreads();

  // ---- closed-form L2..L5 into LDS ----
  const float c2p1 = -0.5f * p1;
  if (tid < 8)
    sm[SM_PLO + tid] = sm[SM_S2 + j1 * 8 + tid] + c2p1 * s1t;
  if (tid < 64)
    sm[SM_PLO + 8 + tid] = sm[SM_S3 + pad32(j1 * 64 + tid)]
                         + sm[SM_A2 + (tid >> 3)] * s1t
                         + c2p1 * sm[SM_S2 + tid];
  if (tid < 512)
    sm[SM_PLO + 72 + tid] = sm[SM_S4 + pad32(j1 * 512 + tid)]
                          + sm[SM_A3 + (tid >> 3)] * s1t
                          + sm[SM_A2 + (tid >> 6)] * sm[SM_S2 + (tid & 63)]
                          + c2p1 * sm[SM_S3 + pad32(tid)];
  {
    float l5v[4];
#pragma unroll
    for (int e = 0; e < 4; ++e) {
      const int q = (tid << 2) + e;
      l5v[e] = l5i[e]
             + sm[SM_A4 + (tid >> 1)] * s1q[e]
             + sm[SM_A3 + (tid >> 4)] * sm[SM_S2 + (q & 63)]
             + sm[SM_A2 + (tid >> 7)] * sm[SM_S3 + pad32(q & 511)]
             + c2p1 * sm[SM_S4 + pad32(q)];
    }
    *(float4*)(sm + SM_L5 + tid * 4) = make_float4(l5v[0], l5v[1], l5v[2], l5v[3]);
  }
  float* outb = out + (size_t)b * NOUT;
  if (tid == 0) outb[j1] = p1;   // level-1 Lyndon word j1
  __syncthreads();

  // ---- gather levels 2..5 via precomputed ranges (no binary search) ----
  const int goff[6]   = {0, 0, 8, 72, 584, 4680};
  const int gsub[6]   = {0, 1, 8, 64, 512, 4096};
  const int ldsoff[6] = {0, 0, 0, 8, 72, 584};
#pragma unroll
  for (int k = 2; k <= 5; ++k) {
    const int rb = (k - 2) * 16 + j1 * 2;
    const int a0 = range_tab[rb];
    const int a1 = range_tab[rb + 1];
    const int v0 = goff[k] + j1 * gsub[k];
    for (int o = a0 + tid; o < a1; o += 1024) {
      int pl = idx_table[o] - v0;
      outb[o] = sm[ldsoff[k] + pl];
    }
  }
  // ---- level 6: float4 coalesced stream + ballot-rank scatter ----
  {
    const float* __restrict__ S6j = S6 + (size_t)j1 * 32768;
    const ull* __restrict__ mk = mask64 + j1 * 512;
    const int* __restrict__ go = grp_off + j1 * 512;
    const int t4i = tid << 2;
#pragma unroll 2
    for (int it = 0; it < 8; ++it) {
      const int pl0 = it * 4096 + t4i;
      const int gg  = pl0 >> 6;
      const ull m   = mk[gg];
      const int gofs = go[gg];
      const float4 x6 = *(const float4*)(S6j + pl0);
      const float4 x5 = *(const float4*)(S5 + pl0);
      const float x6a[4] = {x6.x, x6.y, x6.z, x6.w};
      const float x5a[4] = {x5.x, x5.y, x5.z, x5.w};
      // e-invariant A reads (pl0 = 4*tid within 4096-slab):
      const float a5v = sm[SM_A5 + (pl0 >> 3)];
      const float a4v = sm[SM_A4 + (pl0 >> 6)];
      const float a3v = sm[SM_A3 + (pl0 >> 9)];
      const float a2v = sm[SM_A2 + it];
      const int c63 = pl0 & 63, c511 = pl0 & 511, c4095 = pl0 & 4095;
      const int b0 = pl0 & 63;
#pragma unroll
      for (int e = 0; e < 4; ++e) {
        float v = x6a[e]
                + a5v * s1q[e]
                + a4v * sm[SM_S2 + c63 + e]
                + a3v * sm[SM_S3 + pad32(c511 + e)]
                + a2v * sm[SM_S4 + pad32(c4095 + e)]
                + c2p1 * x5a[e];
        if ((m >> (b0 + e)) & 1ull)
          outb[7764 + gofs + __popcll(m & ((1ull << (b0 + e)) - 1ull))] = v;
      }
    }
  }
}

// ---------- launch ----------
// d_ws layout (16B-aligned head): mask64[4096] ull | idx_table[51360] int |
// blkcnt[256] int | grp_off[4096] int | range_tab[64] int  (~256 KB total)

extern "C" void kernel_launch(void* const* d_in, const int* in_sizes, int n_in,
                              void* d_out, int out_size, void* d_ws, size_t ws_size,
                              hipStream_t stream) {
  const float* sig = (const float*)d_in[0];
  float* out = (float*)d_out;
  ull* mask64    = (ull*)d_ws;                       // 4096 ull
  int* idx_table = (int*)(mask64 + 4096);            // 51360 int
  int* blkcnt    = idx_table + NOUT;                 // 256
  int* grp_off   = blkcnt + 256;                     // 4096
  int* range_tab = grp_off + 4096;                   // 64

  lyndon_stage1<<<257, 1024, 0, stream>>>(idx_table, blkcnt);
  lyndon6_finish<<<256, 1024, 0, stream>>>(blkcnt, idx_table, mask64, grp_off, range_tab);
  logsig_main<<<512, 1024, 0, stream>>>(sig, idx_table, mask64, grp_off, range_tab, out);
}